// Round 10
// baseline (1538.139 us; speedup 1.0000x reference)
//
#include <hip/hip_runtime.h>

#define N_ 25000
#define E_ 200000
#define H_ 512
#define OUT_ 250
#define WSZ (H_ * H_)   // 262144 elems per weight matrix

typedef unsigned short u16;
typedef unsigned int u32;
typedef __bf16 bf16x8 __attribute__((ext_vector_type(8)));
typedef float f32x4 __attribute__((ext_vector_type(4)));

__device__ __forceinline__ u16 f2b(float f) {
  union { float f; u32 u; } c; c.f = f;
  u32 r = c.u + 0x7FFFu + ((c.u >> 16) & 1u);
  return (u16)(r >> 16);
}
// async global->LDS, 16B per lane. LDS dest must be wave-uniform base + lane*16.
__device__ __forceinline__ void async16(const void* g, void* l) {
  __builtin_amdgcn_global_load_lds((__attribute__((address_space(1))) void*)g,
                                   (__attribute__((address_space(3))) void*)l, 16, 0, 0);
}

// ---------------- fused conv_x + histogram ----------------
__global__ void conv_hist(const float* __restrict__ x, u16* __restrict__ xb,
                          const int* __restrict__ edges, int* __restrict__ counts) {
  const int i = blockIdx.x * 256 + threadIdx.x;
  if (i < 3 * E_) {
    int r = i / E_, e = i - r * E_;
    int dst = edges[r * 2 * E_ + E_ + e];
    atomicAdd(&counts[r * N_ + dst], 1);
  }
  if (i < N_ * 512 / 4) {
    const float4 v = *(const float4*)(x + (size_t)i * 4);
    ushort4 o;
    o.x = f2b(v.x); o.y = f2b(v.y); o.z = f2b(v.z); o.w = f2b(v.w);
    *(ushort4*)(xb + (size_t)i * 4) = o;
  }
}

// ---------------- merged weight/bias prep (f32 in, bf16 transposed out) ----
__global__ void prep_all(const float* __restrict__ Wpre, const float* __restrict__ Wpost,
                         const float* __restrict__ Wl, const float* __restrict__ Wr,
                         const float* __restrict__ Wout, const float* __restrict__ bl,
                         const float* __restrict__ bout,
                         u16* __restrict__ WT, u16* __restrict__ WoutT,
                         float* __restrict__ blSum, float* __restrict__ bOutF) {
  __shared__ u16 tile[32][33];
  const int id = blockIdx.z;
  const int tx = blockIdx.x, ty = blockIdx.y;
  const int x = threadIdx.x, y = threadIdx.y;
  if (id == 19) {
    if (tx || ty) return;
    const int t = y * 32 + x;
    for (int t0 = t; t0 < 512; t0 += 256) {
      for (int l = 0; l < 4; ++l)
        blSum[l * 512 + t0] = bl[(l * 3 + 0) * 512 + t0] + bl[(l * 3 + 1) * 512 + t0] +
                              bl[(l * 3 + 2) * 512 + t0];
    }
    if (t < 256) bOutF[t] = (t < OUT_) ? bout[t] : 0.0f;
    return;
  }
  if (id == 18) {
    if (tx >= 8) return;
#pragma unroll
    for (int i = 0; i < 4; ++i) {
      int row = ty * 32 + y + i * 8;   // 0..511
      int col = tx * 32 + x;           // 0..255
      tile[y + i * 8][x] = (col < OUT_) ? f2b(Wout[(size_t)row * OUT_ + col]) : (u16)0;
    }
    __syncthreads();
#pragma unroll
    for (int i = 0; i < 4; ++i)
      WoutT[(tx * 32 + y + i * 8) * 512 + ty * 32 + x] = tile[x][y + i * 8];
    return;
  }
  const float* src = nullptr;
  bool sum3 = false;
  if (id == 0) src = Wpre;
  else if (id == 1) src = Wpost;
  else {
    int li = (id - 2) >> 2, ri = (id - 2) & 3;
    if (ri < 3) src = Wl + (size_t)(li * 3 + ri) * WSZ;
    else { sum3 = true; src = Wr + (size_t)(li * 3) * WSZ; }
  }
#pragma unroll
  for (int i = 0; i < 4; ++i) {
    int row = ty * 32 + y + i * 8;
    int col = tx * 32 + x;
    float f = src[(size_t)row * 512 + col];
    if (sum3) f += src[WSZ + (size_t)row * 512 + col] + src[2 * WSZ + (size_t)row * 512 + col];
    tile[y + i * 8][x] = f2b(f);
  }
  __syncthreads();
#pragma unroll
  for (int i = 0; i < 4; ++i)
    WT[(size_t)id * WSZ + (tx * 32 + y + i * 8) * 512 + ty * 32 + x] = tile[x][y + i * 8];
}

// shuffle-based block scan: one block per relation; also emits invdeg
__global__ __launch_bounds__(1024) void scan_kernel(const int* __restrict__ counts,
                                                    int* __restrict__ rowptr,
                                                    int* __restrict__ cursor,
                                                    float* __restrict__ invdeg) {
  const int r = blockIdx.x;
  const int* cnt = counts + r * N_;
  int* rp = rowptr + r * (N_ + 1);
  int* cur = cursor + r * N_;
  __shared__ int wsum[2][16];
  const int tid = threadIdx.x;
  const int wv = tid >> 6, lane = tid & 63;
  int roff = 0;
  int par = 0;
  for (int base = 0; base < N_; base += 1024, par ^= 1) {
    int v = (base + tid < N_) ? cnt[base + tid] : 0;
    int inc = v;
#pragma unroll
    for (int d = 1; d < 64; d <<= 1) {
      int t = __shfl_up(inc, d, 64);
      if (lane >= d) inc += t;
    }
    if (lane == 63) wsum[par][wv] = inc;
    __syncthreads();
    if (tid < 16) {
      int s = wsum[par][tid];
#pragma unroll
      for (int d = 1; d < 16; d <<= 1) {
        int t = __shfl_up(s, d, 64);
        if (tid >= d) s += t;
      }
      wsum[par][tid] = s;
    }
    __syncthreads();
    int woff = (wv == 0) ? 0 : wsum[par][wv - 1];
    int excl = roff + woff + inc - v;
    if (base + tid < N_) {
      rp[base + tid] = excl; cur[base + tid] = excl;
      invdeg[r * N_ + base + tid] = 1.0f / fmaxf((float)v, 1.0f);
    }
    roff += wsum[par][15];
  }
  if (tid == 0) rp[N_] = roff;
}

__global__ void scatter_kernel(const int* __restrict__ edges, int* __restrict__ cursor,
                               int* __restrict__ colidx) {
  int idx = blockIdx.x * 256 + threadIdx.x;
  if (idx >= 3 * E_) return;
  int r = idx / E_, e = idx - r * E_;
  int src = edges[r * 2 * E_ + e];
  int dst = edges[r * 2 * E_ + E_ + e];
  int pos = atomicAdd(&cursor[r * N_ + dst], 1);
  colidx[r * E_ + pos] = src;
}

// ---------------- mean aggregation (XCD-verified chunk affinity) ----------
__device__ __forceinline__ void acc8(float* acc, uint4 u) {
  union { u32 u; float f; } c;
  c.u = u.x << 16;          acc[0] += c.f;
  c.u = u.x & 0xffff0000u;  acc[1] += c.f;
  c.u = u.y << 16;          acc[2] += c.f;
  c.u = u.y & 0xffff0000u;  acc[3] += c.f;
  c.u = u.z << 16;          acc[4] += c.f;
  c.u = u.z & 0xffff0000u;  acc[5] += c.f;
  c.u = u.w << 16;          acc[6] += c.f;
  c.u = u.w & 0xffff0000u;  acc[7] += c.f;
}

#define AGG_TILES 782            // ceil(N/32)
#define AGG_NT (AGG_TILES * 3)   // tiles per chunk (x3 relations)
// Persistent blocks. Each block reads its PHYSICAL XCD id (s_getreg
// HW_REG_XCC_ID, m09-verified) and processes only feature-chunk==XCD:
// all gathers hit the local 3.2MB L2 slice regardless of dispatch mapping.
// Work pulled from per-chunk atomic queues (wq[8], zeroed per call).
__global__ __launch_bounds__(256) void agg_kernel(const u16* __restrict__ h,
                                                  const int* __restrict__ rowptr,
                                                  const int* __restrict__ colidx,
                                                  const float* __restrict__ invdeg,
                                                  u16* __restrict__ agg,
                                                  int* __restrict__ wq) {
  __shared__ int s_tile;
  u32 xcc;
  asm volatile("s_getreg_b32 %0, hwreg(HW_REG_XCC_ID)" : "=s"(xcc));
  const int chunk = xcc & 7;
  const int wv = threadIdx.x >> 6;
  const int lane = threadIdx.x & 63;
  const int grp = lane >> 3, sub = lane & 7;
  const u16* hb = h + chunk * 64 + sub * 8;   // this lane's 16B in the slice
  for (;;) {
    if (threadIdx.x == 0) s_tile = atomicAdd(&wq[chunk], 1);
    __syncthreads();
    const int t = s_tile;
    __syncthreads();
    if (t >= AGG_NT) break;                   // uniform exit
    const int r = t / AGG_TILES;
    const int ti = t - r * AGG_TILES;
    const int node = ti * 32 + wv * 8 + grp;
    if (node < N_) {
      const int* rp = rowptr + r * (N_ + 1);
      const int* ci = colidx + r * E_;
      const int s = rp[node], e = rp[node + 1];
      float acc[8] = {0.f, 0.f, 0.f, 0.f, 0.f, 0.f, 0.f, 0.f};
      int p = s;
      for (; p + 4 <= e; p += 4) {
        int s0 = ci[p], s1 = ci[p + 1], s2 = ci[p + 2], s3 = ci[p + 3];
        uint4 u0 = *(const uint4*)(hb + (size_t)s0 * 512);
        uint4 u1 = *(const uint4*)(hb + (size_t)s1 * 512);
        uint4 u2 = *(const uint4*)(hb + (size_t)s2 * 512);
        uint4 u3 = *(const uint4*)(hb + (size_t)s3 * 512);
        acc8(acc, u0); acc8(acc, u1); acc8(acc, u2); acc8(acc, u3);
      }
      for (; p < e; ++p) acc8(acc, *(const uint4*)(hb + (size_t)ci[p] * 512));
      const float sc = invdeg[r * N_ + node];
      uint4 o;
      o.x = (u32)f2b(acc[0] * sc) | ((u32)f2b(acc[1] * sc) << 16);
      o.y = (u32)f2b(acc[2] * sc) | ((u32)f2b(acc[3] * sc) << 16);
      o.z = (u32)f2b(acc[4] * sc) | ((u32)f2b(acc[5] * sc) << 16);
      o.w = (u32)f2b(acc[6] * sc) | ((u32)f2b(acc[7] * sc) << 16);
      *(uint4*)(agg + ((size_t)r * N_ + node) * 512 + chunk * 64 + sub * 8) = o;
    }
  }
}

// ---------------- MFMA GEMM (R5 K-loop + LDS-coalesced bf16 epilogue) ------
#define BM 128
#define BN 128
#define BK 64
#define CSTRIDE 136
__global__ __launch_bounds__(256, 4) void gemm_mfma(
    const u16* __restrict__ A0, const u16* __restrict__ A1,
    const u16* __restrict__ A2, const u16* __restrict__ A3,
    const u16* __restrict__ Bt, const float* __restrict__ bias,
    u16* __restrict__ C, float* __restrict__ Cf,
    int M, int G, int ldc, int Nreal, float scale, int leaky) {
  __shared__ __align__(16) u16 shmem[BM * CSTRIDE];  // 34 KB; As/Bs carved below
  u16* As = shmem;                    // BM*BK = 8192 u16
  u16* Bs = shmem + BM * BK;          // BN*BK = 8192 u16
  const int tid = threadIdx.x;
  const int lane = tid & 63;
  const int w = tid >> 6;

  // XCD-aware swizzle of (row-block, col-block)
  const int gx = gridDim.x;
  const int lin = blockIdx.y * gx + blockIdx.x;
  const int gsz = gx * 8;
  const int grp = lin / gsz;
  const int l = lin - grp * gsz;
  const int rem = (int)gridDim.y - grp * 8;
  int by, bx;
  if (rem >= 8) { by = grp * 8 + (l & 7); bx = l >> 3; }
  else          { by = grp * 8 + l % rem; bx = l / rem; }
  const int row0 = by * BM;
  const int col0 = bx * BN;

  // hoisted staging offsets (elements): 4 A-loads + 4 B-loads per thread
  int aOff[4], bOff[4], lOff[4];
#pragma unroll
  for (int i = 0; i < 4; ++i) {
    const int idx = i * 256 + tid;
    const int arow = idx >> 3;
    const int c = (idx & 7) ^ (arow & 7);     // logical chunk for slot idx&7
    int grow = row0 + arow; if (grow >= M) grow = M - 1;
    aOff[i] = grow * 512 + c * 8;
    bOff[i] = (col0 + arow) * 512 + c * 8;
    lOff[i] = idx * 16;                        // LDS byte offset
  }

  // hoisted LDS read offsets
  const int lm = lane & 15;
  const int lk = lane >> 4;                                    // 0..3
  const int x0 = ((lk ^ (lane & 7)) << 3);                     // k0 = 0
  const int x1 = (((4 + lk) ^ (lane & 7)) << 3);               // k0 = 32
  const int wm = (w >> 1) * 64;
  const int wn = (w & 1) * 64;
  int aRow[4], bRow[4];
#pragma unroll
  for (int i = 0; i < 4; ++i) {
    aRow[i] = (wm + i * 16 + lm) * BK;
    bRow[i] = (wn + i * 16 + lm) * BK;
  }

  f32x4 acc[4][4] = {};

  for (int g = 0; g < G; ++g) {
    const u16* Ag = (g == 0) ? A0 : (g == 1) ? A1 : (g == 2) ? A2 : A3;
    const u16* Bg = Bt + ((size_t)g << 18);
#pragma unroll
    for (int ki = 0; ki < 8; ++ki) {
      const u16* Ab = Ag + ki * 64;   // uniform base advance -> saddr form
      const u16* Bb = Bg + ki * 64;
#pragma unroll
      for (int i = 0; i < 4; ++i) {
        async16(Ab + aOff[i], (char*)As + lOff[i]);
        async16(Bb + bOff[i], (char*)Bs + lOff[i]);
      }
      __syncthreads();
      {
        bf16x8 af[4], bfr[4];
#pragma unroll
        for (int i = 0; i < 4; ++i) {
          af[i]  = *(const bf16x8*)((const char*)As + ((aRow[i] + x0) << 1));
          bfr[i] = *(const bf16x8*)((const char*)Bs + ((bRow[i] + x0) << 1));
        }
#pragma unroll
        for (int i = 0; i < 4; ++i)
#pragma unroll
          for (int j = 0; j < 4; ++j)
            acc[i][j] = __builtin_amdgcn_mfma_f32_16x16x32_bf16(af[i], bfr[j], acc[i][j], 0, 0, 0);
#pragma unroll
        for (int i = 0; i < 4; ++i) {
          af[i]  = *(const bf16x8*)((const char*)As + ((aRow[i] + x1) << 1));
          bfr[i] = *(const bf16x8*)((const char*)Bs + ((bRow[i] + x1) << 1));
        }
#pragma unroll
        for (int i = 0; i < 4; ++i)
#pragma unroll
          for (int j = 0; j < 4; ++j)
            acc[i][j] = __builtin_amdgcn_mfma_f32_16x16x32_bf16(af[i], bfr[j], acc[i][j], 0, 0, 0);
      }
      __syncthreads();
    }
  }

  // C/D layout (m89-verified): col = lane&15, row = (lane>>4)*4 + reg
  if (Cf) {  // fp32 scalar path (out-GEMM; masked, small)
    const int crow_base = row0 + wm + (lk << 2);
    const int ccol_base = col0 + wn + lm;
#pragma unroll
    for (int i = 0; i < 4; ++i) {
#pragma unroll
      for (int j = 0; j < 4; ++j) {
        const int ccol = ccol_base + j * 16;
        const float badd = bias ? bias[ccol] : 0.0f;
#pragma unroll
        for (int rg = 0; rg < 4; ++rg) {
          const int crow = crow_base + i * 16 + rg;
          if (crow < M && ccol < Nreal) {
            float v = (acc[i][j][rg] + badd) * scale;
            if (leaky) v = (v >= 0.0f) ? v : 0.2f * v;
            Cf[(size_t)crow * ldc + ccol] = v;
          }
        }
      }
    }
    return;
  }
  // bf16 path: transpose through LDS, store coalesced (Nreal==ldc==512 here)
  {
    const int lrow_base = wm + (lk << 2);
    const int lcol_base = wn + lm;
#pragma unroll
    for (int i = 0; i < 4; ++i) {
#pragma unroll
      for (int j = 0; j < 4; ++j) {
        const int lcol = lcol_base + j * 16;
        const float badd = bias ? bias[col0 + lcol] : 0.0f;
#pragma unroll
        for (int rg = 0; rg < 4; ++rg) {
          const int lrow = lrow_base + i * 16 + rg;
          float v = (acc[i][j][rg] + badd) * scale;
          if (leaky) v = (v >= 0.0f) ? v : 0.2f * v;
          shmem[lrow * CSTRIDE + lcol] = f2b(v);
        }
      }
    }
    __syncthreads();
    const int rr = tid >> 4;           // 0..15
    const int c8 = (tid & 15) * 8;     // col chunk (8 u16 = 16 B)
#pragma unroll
    for (int pass = 0; pass < 8; ++pass) {
      const int r = pass * 16 + rr;    // 0..127
      const int crow = row0 + r;
      if (crow < M) {
        uint4 v = *(const uint4*)&shmem[r * CSTRIDE + c8];
        *(uint4*)(C + (size_t)crow * ldc + col0 + c8) = v;
      }
    }
  }
}

// ---------------- launch ----------------
extern "C" void kernel_launch(void* const* d_in, const int* in_sizes, int n_in,
                              void* d_out, int out_size, void* d_ws, size_t ws_size,
                              hipStream_t stream) {
  const float* x     = (const float*)d_in[0];
  const float* Wpre  = (const float*)d_in[1];
  const float* Wpost = (const float*)d_in[2];
  const float* Wl    = (const float*)d_in[3];
  const float* Wr    = (const float*)d_in[4];
  const float* bl    = (const float*)d_in[5];
  const float* Wout  = (const float*)d_in[6];
  const float* bout  = (const float*)d_in[7];
  const int*   edges = (const int*)d_in[8];
  float* out = (float*)d_out;

  char* p = (char*)d_ws;
  auto alloc = [&](size_t b) { void* q = (void*)p; p += (b + 255) & ~(size_t)255; return q; };
  u16*   WT     = (u16*)alloc((size_t)18 * WSZ * 2);
  u16*   WoutT  = (u16*)alloc((size_t)256 * 512 * 2);
  float* blSum  = (float*)alloc(4 * 512 * 4);
  float* bOutF  = (float*)alloc(256 * 4);
  u16*   hA     = (u16*)alloc((size_t)N_ * 512 * 2);
  u16*   hB     = (u16*)alloc((size_t)N_ * 512 * 2);
  u16*   aggb   = (u16*)alloc((size_t)3 * N_ * 512 * 2);
  int*   counts = (int*)alloc(3 * N_ * 4);
  float* invdeg = (float*)alloc(3 * N_ * 4);
  int*   rowptr = (int*)alloc(3 * (N_ + 1) * 4);
  int*   cursor = (int*)alloc(3 * N_ * 4);
  int*   colidx = (int*)alloc((size_t)3 * E_ * 4);
  int*   wq     = (int*)alloc(32 * 4);        // 4 layers x 8 chunk queues
  // xb (bf16 copy of x) aliases aggb: dead before aggb is first written.
  u16*   xb     = aggb;

  hipMemsetAsync(counts, 0, 3 * N_ * 4, stream);
  hipMemsetAsync(wq, 0, 32 * 4, stream);
  conv_hist<<<(N_ * 512 / 4 + 255) / 256, 256, 0, stream>>>(x, xb, edges, counts);
  prep_all<<<dim3(16, 16, 20), dim3(32, 8), 0, stream>>>(Wpre, Wpost, Wl, Wr, Wout, bl, bout,
                                                          WT, WoutT, blSum, bOutF);
  scan_kernel<<<3, 1024, 0, stream>>>(counts, rowptr, cursor, invdeg);
  scatter_kernel<<<(3 * E_ + 255) / 256, 256, 0, stream>>>(edges, cursor, colidx);

  const dim3 blk(256);
  const dim3 g512(512 / BN, (N_ + BM - 1) / BM);
  // h = leaky(leaky(x@Wpre)@Wpost)
  gemm_mfma<<<g512, blk, 0, stream>>>(xb, xb, xb, xb, WT, nullptr, hA, nullptr,
                                      N_, 1, 512, 512, 1.0f, 1);
  gemm_mfma<<<g512, blk, 0, stream>>>(hA, hA, hA, hA, WT + WSZ, nullptr, hB, nullptr,
                                      N_, 1, 512, 512, 1.0f, 1);

  u16* hc = hB; u16* hn = hA;
  for (int l = 0; l < 4; ++l) {
    agg_kernel<<<2048, blk, 0, stream>>>(hc, rowptr, colidx, invdeg, aggb, wq + l * 8);
    gemm_mfma<<<g512, blk, 0, stream>>>(aggb, aggb + (size_t)N_ * 512, aggb + (size_t)2 * N_ * 512, hc,
                                        WT + (size_t)(2 + 4 * l) * WSZ, blSum + l * 512, hn, nullptr,
                                        N_, 4, 512, 512, 1.0f / 3.0f, 1);
    u16* t = hc; hc = hn; hn = t;
  }
  const dim3 gout(256 / BN, (N_ + BM - 1) / BM);
  gemm_mfma<<<gout, blk, 0, stream>>>(hc, hc, hc, hc, WoutT, bOutF, nullptr, out,
                                      N_, 1, OUT_, OUT_, 1.0f, 0);
}

// Round 11
// 932.649 us; speedup vs baseline: 1.6492x; 1.6492x over previous
//
#include <hip/hip_runtime.h>

#define N_ 25000
#define E_ 200000
#define H_ 512
#define OUT_ 250
#define WSZ (H_ * H_)   // 262144 elems per weight matrix

typedef unsigned short u16;
typedef unsigned int u32;
typedef __bf16 bf16x8 __attribute__((ext_vector_type(8)));
typedef float f32x4 __attribute__((ext_vector_type(4)));

__device__ __forceinline__ u16 f2b(float f) {
  union { float f; u32 u; } c; c.f = f;
  u32 r = c.u + 0x7FFFu + ((c.u >> 16) & 1u);
  return (u16)(r >> 16);
}
// async global->LDS, 16B per lane. LDS dest must be wave-uniform base + lane*16.
__device__ __forceinline__ void async16(const void* g, void* l) {
  __builtin_amdgcn_global_load_lds((__attribute__((address_space(1))) void*)g,
                                   (__attribute__((address_space(3))) void*)l, 16, 0, 0);
}

// ---------------- fused conv_x + histogram ----------------
__global__ void conv_hist(const float* __restrict__ x, u16* __restrict__ xb,
                          const int* __restrict__ edges, int* __restrict__ counts) {
  const int i = blockIdx.x * 256 + threadIdx.x;
  if (i < 3 * E_) {
    int r = i / E_, e = i - r * E_;
    int dst = edges[r * 2 * E_ + E_ + e];
    atomicAdd(&counts[r * N_ + dst], 1);
  }
  if (i < N_ * 512 / 4) {
    const float4 v = *(const float4*)(x + (size_t)i * 4);
    ushort4 o;
    o.x = f2b(v.x); o.y = f2b(v.y); o.z = f2b(v.z); o.w = f2b(v.w);
    *(ushort4*)(xb + (size_t)i * 4) = o;
  }
}

// ---------------- merged weight/bias prep (f32 in, bf16 transposed out) ----
__global__ void prep_all(const float* __restrict__ Wpre, const float* __restrict__ Wpost,
                         const float* __restrict__ Wl, const float* __restrict__ Wr,
                         const float* __restrict__ Wout, const float* __restrict__ bl,
                         const float* __restrict__ bout,
                         u16* __restrict__ WT, u16* __restrict__ WoutT,
                         float* __restrict__ blSum, float* __restrict__ bOutF) {
  __shared__ u16 tile[32][33];
  const int id = blockIdx.z;
  const int tx = blockIdx.x, ty = blockIdx.y;
  const int x = threadIdx.x, y = threadIdx.y;
  if (id == 19) {
    if (tx || ty) return;
    const int t = y * 32 + x;
    for (int t0 = t; t0 < 512; t0 += 256) {
      for (int l = 0; l < 4; ++l)
        blSum[l * 512 + t0] = bl[(l * 3 + 0) * 512 + t0] + bl[(l * 3 + 1) * 512 + t0] +
                              bl[(l * 3 + 2) * 512 + t0];
    }
    if (t < 256) bOutF[t] = (t < OUT_) ? bout[t] : 0.0f;
    return;
  }
  if (id == 18) {
    if (tx >= 8) return;
#pragma unroll
    for (int i = 0; i < 4; ++i) {
      int row = ty * 32 + y + i * 8;   // 0..511
      int col = tx * 32 + x;           // 0..255
      tile[y + i * 8][x] = (col < OUT_) ? f2b(Wout[(size_t)row * OUT_ + col]) : (u16)0;
    }
    __syncthreads();
#pragma unroll
    for (int i = 0; i < 4; ++i)
      WoutT[(tx * 32 + y + i * 8) * 512 + ty * 32 + x] = tile[x][y + i * 8];
    return;
  }
  const float* src = nullptr;
  bool sum3 = false;
  if (id == 0) src = Wpre;
  else if (id == 1) src = Wpost;
  else {
    int li = (id - 2) >> 2, ri = (id - 2) & 3;
    if (ri < 3) src = Wl + (size_t)(li * 3 + ri) * WSZ;
    else { sum3 = true; src = Wr + (size_t)(li * 3) * WSZ; }
  }
#pragma unroll
  for (int i = 0; i < 4; ++i) {
    int row = ty * 32 + y + i * 8;
    int col = tx * 32 + x;
    float f = src[(size_t)row * 512 + col];
    if (sum3) f += src[WSZ + (size_t)row * 512 + col] + src[2 * WSZ + (size_t)row * 512 + col];
    tile[y + i * 8][x] = f2b(f);
  }
  __syncthreads();
#pragma unroll
  for (int i = 0; i < 4; ++i)
    WT[(size_t)id * WSZ + (tx * 32 + y + i * 8) * 512 + ty * 32 + x] = tile[x][y + i * 8];
}

// shuffle-based block scan: one block per relation; also emits invdeg
__global__ __launch_bounds__(1024) void scan_kernel(const int* __restrict__ counts,
                                                    int* __restrict__ rowptr,
                                                    int* __restrict__ cursor,
                                                    float* __restrict__ invdeg) {
  const int r = blockIdx.x;
  const int* cnt = counts + r * N_;
  int* rp = rowptr + r * (N_ + 1);
  int* cur = cursor + r * N_;
  __shared__ int wsum[2][16];
  const int tid = threadIdx.x;
  const int wv = tid >> 6, lane = tid & 63;
  int roff = 0;
  int par = 0;
  for (int base = 0; base < N_; base += 1024, par ^= 1) {
    int v = (base + tid < N_) ? cnt[base + tid] : 0;
    int inc = v;
#pragma unroll
    for (int d = 1; d < 64; d <<= 1) {
      int t = __shfl_up(inc, d, 64);
      if (lane >= d) inc += t;
    }
    if (lane == 63) wsum[par][wv] = inc;
    __syncthreads();
    if (tid < 16) {
      int s = wsum[par][tid];
#pragma unroll
      for (int d = 1; d < 16; d <<= 1) {
        int t = __shfl_up(s, d, 64);
        if (tid >= d) s += t;
      }
      wsum[par][tid] = s;
    }
    __syncthreads();
    int woff = (wv == 0) ? 0 : wsum[par][wv - 1];
    int excl = roff + woff + inc - v;
    if (base + tid < N_) {
      rp[base + tid] = excl; cur[base + tid] = excl;
      invdeg[r * N_ + base + tid] = 1.0f / fmaxf((float)v, 1.0f);
    }
    roff += wsum[par][15];
  }
  if (tid == 0) rp[N_] = roff;
}

__global__ void scatter_kernel(const int* __restrict__ edges, int* __restrict__ cursor,
                               int* __restrict__ colidx) {
  int idx = blockIdx.x * 256 + threadIdx.x;
  if (idx >= 3 * E_) return;
  int r = idx / E_, e = idx - r * E_;
  int src = edges[r * 2 * E_ + e];
  int dst = edges[r * 2 * E_ + E_ + e];
  int pos = atomicAdd(&cursor[r * N_ + dst], 1);
  colidx[r * E_ + pos] = src;
}

// ---------------- mean aggregation (XCD-verified chunk affinity) ----------
__device__ __forceinline__ void acc8(float* acc, uint4 u) {
  union { u32 u; float f; } c;
  c.u = u.x << 16;          acc[0] += c.f;
  c.u = u.x & 0xffff0000u;  acc[1] += c.f;
  c.u = u.y << 16;          acc[2] += c.f;
  c.u = u.y & 0xffff0000u;  acc[3] += c.f;
  c.u = u.z << 16;          acc[4] += c.f;
  c.u = u.z & 0xffff0000u;  acc[5] += c.f;
  c.u = u.w << 16;          acc[6] += c.f;
  c.u = u.w & 0xffff0000u;  acc[7] += c.f;
}

#define AGG_TILES 782            // ceil(N/32)
#define AGG_NT (AGG_TILES * 3)   // tiles per chunk (x3 relations)
#define AGG_B 8                  // tiles per queue pop
// Persistent blocks; chunk = physical XCD (s_getreg HW_REG_XCC_ID, m09) so
// every gather hits the local 3.2MB L2 slice (R10: FETCH 263->52MB verified).
// R10 fix: per-chunk counters padded to 256B (own cacheline, stays in local
// L2 -- no cross-XCD line bounce) and pops batched x8 (2346 -> ~294 pops).
__global__ __launch_bounds__(256) void agg_kernel(const u16* __restrict__ h,
                                                  const int* __restrict__ rowptr,
                                                  const int* __restrict__ colidx,
                                                  const float* __restrict__ invdeg,
                                                  u16* __restrict__ agg,
                                                  int* __restrict__ wq) {
  __shared__ int s_base;
  u32 xcc;
  asm volatile("s_getreg_b32 %0, hwreg(HW_REG_XCC_ID)" : "=s"(xcc));
  const int chunk = xcc & 7;
  const int wv = threadIdx.x >> 6;
  const int lane = threadIdx.x & 63;
  const int grp = lane >> 3, sub = lane & 7;
  const u16* hb = h + chunk * 64 + sub * 8;   // this lane's 16B in the slice
  for (;;) {
    if (threadIdx.x == 0) s_base = atomicAdd(&wq[chunk * 64], AGG_B);
    __syncthreads();
    const int base = s_base;
    __syncthreads();
    if (base >= AGG_NT) break;                // uniform exit
    const int end = (base + AGG_B < AGG_NT) ? base + AGG_B : AGG_NT;
    for (int t = base; t < end; ++t) {
      const int r = t / AGG_TILES;
      const int ti = t - r * AGG_TILES;
      const int node = ti * 32 + wv * 8 + grp;
      if (node >= N_) continue;
      const int* rp = rowptr + r * (N_ + 1);
      const int* ci = colidx + r * E_;
      const int s = rp[node], e = rp[node + 1];
      float acc[8] = {0.f, 0.f, 0.f, 0.f, 0.f, 0.f, 0.f, 0.f};
      int p = s;
      for (; p + 4 <= e; p += 4) {
        int s0 = ci[p], s1 = ci[p + 1], s2 = ci[p + 2], s3 = ci[p + 3];
        uint4 u0 = *(const uint4*)(hb + (size_t)s0 * 512);
        uint4 u1 = *(const uint4*)(hb + (size_t)s1 * 512);
        uint4 u2 = *(const uint4*)(hb + (size_t)s2 * 512);
        uint4 u3 = *(const uint4*)(hb + (size_t)s3 * 512);
        acc8(acc, u0); acc8(acc, u1); acc8(acc, u2); acc8(acc, u3);
      }
      for (; p < e; ++p) acc8(acc, *(const uint4*)(hb + (size_t)ci[p] * 512));
      const float sc = invdeg[r * N_ + node];
      uint4 o;
      o.x = (u32)f2b(acc[0] * sc) | ((u32)f2b(acc[1] * sc) << 16);
      o.y = (u32)f2b(acc[2] * sc) | ((u32)f2b(acc[3] * sc) << 16);
      o.z = (u32)f2b(acc[4] * sc) | ((u32)f2b(acc[5] * sc) << 16);
      o.w = (u32)f2b(acc[6] * sc) | ((u32)f2b(acc[7] * sc) << 16);
      *(uint4*)(agg + ((size_t)r * N_ + node) * 512 + chunk * 64 + sub * 8) = o;
    }
  }
}

// ---------------- MFMA GEMM (R5 K-loop + LDS-coalesced bf16 epilogue) ------
#define BM 128
#define BN 128
#define BK 64
#define CSTRIDE 136
__global__ __launch_bounds__(256, 4) void gemm_mfma(
    const u16* __restrict__ A0, const u16* __restrict__ A1,
    const u16* __restrict__ A2, const u16* __restrict__ A3,
    const u16* __restrict__ Bt, const float* __restrict__ bias,
    u16* __restrict__ C, float* __restrict__ Cf,
    int M, int G, int ldc, int Nreal, float scale, int leaky) {
  __shared__ __align__(16) u16 shmem[BM * CSTRIDE];  // 34 KB; As/Bs carved below
  u16* As = shmem;                    // BM*BK = 8192 u16
  u16* Bs = shmem + BM * BK;          // BN*BK = 8192 u16
  const int tid = threadIdx.x;
  const int lane = tid & 63;
  const int w = tid >> 6;

  // XCD-aware swizzle of (row-block, col-block)
  const int gx = gridDim.x;
  const int lin = blockIdx.y * gx + blockIdx.x;
  const int gsz = gx * 8;
  const int grp = lin / gsz;
  const int l = lin - grp * gsz;
  const int rem = (int)gridDim.y - grp * 8;
  int by, bx;
  if (rem >= 8) { by = grp * 8 + (l & 7); bx = l >> 3; }
  else          { by = grp * 8 + l % rem; bx = l / rem; }
  const int row0 = by * BM;
  const int col0 = bx * BN;

  // hoisted staging offsets (elements): 4 A-loads + 4 B-loads per thread
  int aOff[4], bOff[4], lOff[4];
#pragma unroll
  for (int i = 0; i < 4; ++i) {
    const int idx = i * 256 + tid;
    const int arow = idx >> 3;
    const int c = (idx & 7) ^ (arow & 7);     // logical chunk for slot idx&7
    int grow = row0 + arow; if (grow >= M) grow = M - 1;
    aOff[i] = grow * 512 + c * 8;
    bOff[i] = (col0 + arow) * 512 + c * 8;
    lOff[i] = idx * 16;                        // LDS byte offset
  }

  // hoisted LDS read offsets
  const int lm = lane & 15;
  const int lk = lane >> 4;                                    // 0..3
  const int x0 = ((lk ^ (lane & 7)) << 3);                     // k0 = 0
  const int x1 = (((4 + lk) ^ (lane & 7)) << 3);               // k0 = 32
  const int wm = (w >> 1) * 64;
  const int wn = (w & 1) * 64;
  int aRow[4], bRow[4];
#pragma unroll
  for (int i = 0; i < 4; ++i) {
    aRow[i] = (wm + i * 16 + lm) * BK;
    bRow[i] = (wn + i * 16 + lm) * BK;
  }

  f32x4 acc[4][4] = {};

  for (int g = 0; g < G; ++g) {
    const u16* Ag = (g == 0) ? A0 : (g == 1) ? A1 : (g == 2) ? A2 : A3;
    const u16* Bg = Bt + ((size_t)g << 18);
#pragma unroll
    for (int ki = 0; ki < 8; ++ki) {
      const u16* Ab = Ag + ki * 64;   // uniform base advance -> saddr form
      const u16* Bb = Bg + ki * 64;
#pragma unroll
      for (int i = 0; i < 4; ++i) {
        async16(Ab + aOff[i], (char*)As + lOff[i]);
        async16(Bb + bOff[i], (char*)Bs + lOff[i]);
      }
      __syncthreads();
      {
        bf16x8 af[4], bfr[4];
#pragma unroll
        for (int i = 0; i < 4; ++i) {
          af[i]  = *(const bf16x8*)((const char*)As + ((aRow[i] + x0) << 1));
          bfr[i] = *(const bf16x8*)((const char*)Bs + ((bRow[i] + x0) << 1));
        }
#pragma unroll
        for (int i = 0; i < 4; ++i)
#pragma unroll
          for (int j = 0; j < 4; ++j)
            acc[i][j] = __builtin_amdgcn_mfma_f32_16x16x32_bf16(af[i], bfr[j], acc[i][j], 0, 0, 0);
#pragma unroll
        for (int i = 0; i < 4; ++i) {
          af[i]  = *(const bf16x8*)((const char*)As + ((aRow[i] + x1) << 1));
          bfr[i] = *(const bf16x8*)((const char*)Bs + ((bRow[i] + x1) << 1));
        }
#pragma unroll
        for (int i = 0; i < 4; ++i)
#pragma unroll
          for (int j = 0; j < 4; ++j)
            acc[i][j] = __builtin_amdgcn_mfma_f32_16x16x32_bf16(af[i], bfr[j], acc[i][j], 0, 0, 0);
      }
      __syncthreads();
    }
  }

  // C/D layout (m89-verified): col = lane&15, row = (lane>>4)*4 + reg
  if (Cf) {  // fp32 scalar path (out-GEMM; masked, small)
    const int crow_base = row0 + wm + (lk << 2);
    const int ccol_base = col0 + wn + lm;
#pragma unroll
    for (int i = 0; i < 4; ++i) {
#pragma unroll
      for (int j = 0; j < 4; ++j) {
        const int ccol = ccol_base + j * 16;
        const float badd = bias ? bias[ccol] : 0.0f;
#pragma unroll
        for (int rg = 0; rg < 4; ++rg) {
          const int crow = crow_base + i * 16 + rg;
          if (crow < M && ccol < Nreal) {
            float v = (acc[i][j][rg] + badd) * scale;
            if (leaky) v = (v >= 0.0f) ? v : 0.2f * v;
            Cf[(size_t)crow * ldc + ccol] = v;
          }
        }
      }
    }
    return;
  }
  // bf16 path: transpose through LDS, store coalesced (Nreal==ldc==512 here)
  {
    const int lrow_base = wm + (lk << 2);
    const int lcol_base = wn + lm;
#pragma unroll
    for (int i = 0; i < 4; ++i) {
#pragma unroll
      for (int j = 0; j < 4; ++j) {
        const int lcol = lcol_base + j * 16;
        const float badd = bias ? bias[col0 + lcol] : 0.0f;
#pragma unroll
        for (int rg = 0; rg < 4; ++rg) {
          const int lrow = lrow_base + i * 16 + rg;
          float v = (acc[i][j][rg] + badd) * scale;
          if (leaky) v = (v >= 0.0f) ? v : 0.2f * v;
          shmem[lrow * CSTRIDE + lcol] = f2b(v);
        }
      }
    }
    __syncthreads();
    const int rr = tid >> 4;           // 0..15
    const int c8 = (tid & 15) * 8;     // col chunk (8 u16 = 16 B)
#pragma unroll
    for (int pass = 0; pass < 8; ++pass) {
      const int r = pass * 16 + rr;    // 0..127
      const int crow = row0 + r;
      if (crow < M) {
        uint4 v = *(const uint4*)&shmem[r * CSTRIDE + c8];
        *(uint4*)(C + (size_t)crow * ldc + col0 + c8) = v;
      }
    }
  }
}

// ---------------- launch ----------------
extern "C" void kernel_launch(void* const* d_in, const int* in_sizes, int n_in,
                              void* d_out, int out_size, void* d_ws, size_t ws_size,
                              hipStream_t stream) {
  const float* x     = (const float*)d_in[0];
  const float* Wpre  = (const float*)d_in[1];
  const float* Wpost = (const float*)d_in[2];
  const float* Wl    = (const float*)d_in[3];
  const float* Wr    = (const float*)d_in[4];
  const float* bl    = (const float*)d_in[5];
  const float* Wout  = (const float*)d_in[6];
  const float* bout  = (const float*)d_in[7];
  const int*   edges = (const int*)d_in[8];
  float* out = (float*)d_out;

  char* p = (char*)d_ws;
  auto alloc = [&](size_t b) { void* q = (void*)p; p += (b + 255) & ~(size_t)255; return q; };
  u16*   WT     = (u16*)alloc((size_t)18 * WSZ * 2);
  u16*   WoutT  = (u16*)alloc((size_t)256 * 512 * 2);
  float* blSum  = (float*)alloc(4 * 512 * 4);
  float* bOutF  = (float*)alloc(256 * 4);
  u16*   hA     = (u16*)alloc((size_t)N_ * 512 * 2);
  u16*   hB     = (u16*)alloc((size_t)N_ * 512 * 2);
  u16*   aggb   = (u16*)alloc((size_t)3 * N_ * 512 * 2);
  int*   counts = (int*)alloc(3 * N_ * 4);
  float* invdeg = (float*)alloc(3 * N_ * 4);
  int*   rowptr = (int*)alloc(3 * (N_ + 1) * 4);
  int*   cursor = (int*)alloc(3 * N_ * 4);
  int*   colidx = (int*)alloc((size_t)3 * E_ * 4);
  int*   wq     = (int*)alloc(4 * 8 * 64 * 4);  // 4 layers x 8 chunks x 256B
  // xb (bf16 copy of x) aliases aggb: dead before aggb is first written.
  u16*   xb     = aggb;

  hipMemsetAsync(counts, 0, 3 * N_ * 4, stream);
  hipMemsetAsync(wq, 0, 4 * 8 * 64 * 4, stream);
  conv_hist<<<(N_ * 512 / 4 + 255) / 256, 256, 0, stream>>>(x, xb, edges, counts);
  prep_all<<<dim3(16, 16, 20), dim3(32, 8), 0, stream>>>(Wpre, Wpost, Wl, Wr, Wout, bl, bout,
                                                          WT, WoutT, blSum, bOutF);
  scan_kernel<<<3, 1024, 0, stream>>>(counts, rowptr, cursor, invdeg);
  scatter_kernel<<<(3 * E_ + 255) / 256, 256, 0, stream>>>(edges, cursor, colidx);

  const dim3 blk(256);
  const dim3 g512(512 / BN, (N_ + BM - 1) / BM);
  // h = leaky(leaky(x@Wpre)@Wpost)
  gemm_mfma<<<g512, blk, 0, stream>>>(xb, xb, xb, xb, WT, nullptr, hA, nullptr,
                                      N_, 1, 512, 512, 1.0f, 1);
  gemm_mfma<<<g512, blk, 0, stream>>>(hA, hA, hA, hA, WT + WSZ, nullptr, hB, nullptr,
                                      N_, 1, 512, 512, 1.0f, 1);

  u16* hc = hB; u16* hn = hA;
  for (int l = 0; l < 4; ++l) {
    agg_kernel<<<2048, blk, 0, stream>>>(hc, rowptr, colidx, invdeg, aggb, wq + l * 512);
    gemm_mfma<<<g512, blk, 0, stream>>>(aggb, aggb + (size_t)N_ * 512, aggb + (size_t)2 * N_ * 512, hc,
                                        WT + (size_t)(2 + 4 * l) * WSZ, blSum + l * 512, hn, nullptr,
                                        N_, 4, 512, 512, 1.0f / 3.0f, 1);
    u16* t = hc; hc = hn; hn = t;
  }
  const dim3 gout(256 / BN, (N_ + BM - 1) / BM);
  gemm_mfma<<<gout, blk, 0, stream>>>(hc, hc, hc, hc, WoutT, bOutF, nullptr, out,
                                      N_, 1, OUT_, OUT_, 1.0f, 0);
}